// Round 5
// baseline (371.331 us; speedup 1.0000x reference)
//
#include <hip/hip_runtime.h>
#include <stdint.h>
#include <math.h>

#define HIST_BINS   65536
#define HIST_WORDS8 16384          // uint32 words, 4 packed uint8 bins each (64 KB LDS)

typedef float f4 __attribute__((ext_vector_type(4)));

__device__ __forceinline__ f4 ldnt(const f4* p){ return __builtin_nontemporal_load(p); }

// ---------- float <-> monotonic uint key (for atomic min/max on floats) ----------
__device__ __forceinline__ uint32_t f2key(float f){
    uint32_t u = __float_as_uint(f);
    return (u & 0x80000000u) ? ~u : (u | 0x80000000u);
}
__device__ __forceinline__ float key2f(uint32_t k){
    uint32_t u = (k & 0x80000000u) ? (k ^ 0x80000000u) : ~k;
    return __uint_as_float(u);
}

// ws layout (uint32 words):
//   [0 .. 65535]     final uint32 joint histogram (256 KB)
//   [65536 .. 65539] minmax keys: min_x, max_x, min_y, max_y   (padded to 65600)
//   [65600 .. 65855] rsum[256]  (row sums -> p_x counts)
//   [65856 .. 66111] csum[256]  (col sums -> p_y counts)
//   [66112 ...]      per-block packed-uint8 partial histograms (nblk * 64 KB)

__global__ void init_kernel(uint32_t* __restrict__ mm, uint32_t* __restrict__ csum){
    int t = threadIdx.x;
    if (t < 4) mm[t] = (t & 1) ? 0u : 0xFFFFFFFFu;  // min slots=+infkey, max slots=0
    csum[t] = 0u;
}

__device__ __forceinline__ void mm4(f4 a, float& mn, float& mx){
    mn = fminf(mn, fminf(fminf(a[0], a[1]), fminf(a[2], a[3])));
    mx = fmaxf(mx, fmaxf(fmaxf(a[0], a[1]), fmaxf(a[2], a[3])));
}

// Blocks [0, nblk_per) scan x; [nblk_per, 2*nblk_per) scan y.
// Each block owns ONE CONTIGUOUS segment; 8 independent loads in flight.
__global__ void __launch_bounds__(1024)
minmax_kernel(const f4* __restrict__ x, const f4* __restrict__ y,
              uint32_t* __restrict__ mm, int n4, int nblk_per){
    int isy = (blockIdx.x >= (unsigned)nblk_per) ? 1 : 0;
    const f4* __restrict__ src = isy ? y : x;
    int bid = blockIdx.x - isy * nblk_per;
    int seg = n4 / nblk_per;           // contiguous elements per block
    int base = bid * seg;
    const int chunk = 1024 * 8;
    float mn = INFINITY, mx = -INFINITY;
    int off = 0;
    for (; off + chunk <= seg; off += chunk){
        const f4* p = src + base + off + threadIdx.x;
        f4 v0 = p[0],        v1 = p[1024],     v2 = p[2 * 1024], v3 = p[3 * 1024];
        f4 v4 = p[4 * 1024], v5 = p[5 * 1024], v6 = p[6 * 1024], v7 = p[7 * 1024];
        mm4(v0, mn, mx); mm4(v1, mn, mx); mm4(v2, mn, mx); mm4(v3, mn, mx);
        mm4(v4, mn, mx); mm4(v5, mn, mx); mm4(v6, mn, mx); mm4(v7, mn, mx);
    }
    for (int i = base + off + threadIdx.x; i < base + seg; i += 1024) mm4(src[i], mn, mx);
    if (bid == nblk_per - 1)
        for (int i = nblk_per * seg + threadIdx.x; i < n4; i += 1024) mm4(src[i], mn, mx);

    #pragma unroll
    for (int o = 32; o > 0; o >>= 1){
        mn = fminf(mn, __shfl_down(mn, o, 64));
        mx = fmaxf(mx, __shfl_down(mx, o, 64));
    }
    __shared__ float smn[16], smx[16];
    int lane = threadIdx.x & 63, wid = threadIdx.x >> 6;
    if (lane == 0){ smn[wid] = mn; smx[wid] = mx; }
    __syncthreads();
    if (threadIdx.x == 0){
        for (int w = 1; w < 16; ++w){ mn = fminf(mn, smn[w]); mx = fmaxf(mx, smx[w]); }
        atomicMin(&mm[isy * 2 + 0], f2key(mn));
        atomicMax(&mm[isy * 2 + 1], f2key(mx));
    }
}

__device__ __forceinline__ void bin_pair(float vx, float vy,
                                         float mnx, float sx, float mny, float sy,
                                         uint32_t* lh){
    int ix = (int)floorf((vx - mnx) * sx);
    int iy = (int)floorf((vy - mny) * sy);
    ix = ix < 0 ? 0 : (ix > 255 ? 255 : ix);
    iy = iy < 0 ? 0 : (iy > 255 ? 255 : iy);
    uint32_t bin = ((uint32_t)ix << 8) | (uint32_t)iy;
    atomicAdd(&lh[bin >> 2], 1u << ((bin & 3u) * 8u));
}

__device__ __forceinline__ void bin4(f4 a, f4 b,
                                     float mnx, float sx, float mny, float sy,
                                     uint32_t* lh){
    bin_pair(a[0], b[0], mnx, sx, mny, sy, lh);
    bin_pair(a[1], b[1], mnx, sx, mny, sy, lh);
    bin_pair(a[2], b[2], mnx, sx, mny, sy, lh);
    bin_pair(a[3], b[3], mnx, sx, mny, sy, lh);
}

__global__ void __launch_bounds__(1024)
hist_kernel(const f4* __restrict__ x, const f4* __restrict__ y,
            const uint32_t* __restrict__ mm, uint32_t* __restrict__ out32,
            int n4, int atomic_flush){
    __shared__ uint32_t lh[HIST_WORDS8];   // 64 KB: 65536 uint8 bins packed 4/word
    for (int w = threadIdx.x; w < HIST_WORDS8; w += blockDim.x) lh[w] = 0u;
    __syncthreads();

    float mnx = key2f(mm[0]);
    float sx  = 256.0f / ((key2f(mm[1]) - mnx) + 1e-8f);
    float mny = key2f(mm[2]);
    float sy  = 256.0f / ((key2f(mm[3]) - mny) + 1e-8f);

    int seg  = n4 / gridDim.x;            // contiguous segment per block
    int base = blockIdx.x * seg;
    const int chunk = 1024 * 4;
    int off = 0;
    for (; off + chunk <= seg; off += chunk){
        const f4* px = x + base + off + threadIdx.x;
        const f4* py = y + base + off + threadIdx.x;
        f4 a0 = ldnt(px),            a1 = ldnt(px + 1024);
        f4 a2 = ldnt(px + 2 * 1024), a3 = ldnt(px + 3 * 1024);
        f4 b0 = ldnt(py),            b1 = ldnt(py + 1024);
        f4 b2 = ldnt(py + 2 * 1024), b3 = ldnt(py + 3 * 1024);
        bin4(a0, b0, mnx, sx, mny, sy, lh);
        bin4(a1, b1, mnx, sx, mny, sy, lh);
        bin4(a2, b2, mnx, sx, mny, sy, lh);
        bin4(a3, b3, mnx, sx, mny, sy, lh);
    }
    for (int i = base + off + threadIdx.x; i < base + seg; i += 1024)
        bin4(x[i], y[i], mnx, sx, mny, sy, lh);
    if (blockIdx.x == gridDim.x - 1)
        for (int i = gridDim.x * seg + threadIdx.x; i < n4; i += 1024)
            bin4(x[i], y[i], mnx, sx, mny, sy, lh);
    __syncthreads();

    if (!atomic_flush){
        uint32_t* part = out32 + (size_t)blockIdx.x * HIST_WORDS8;
        for (int w = threadIdx.x; w < HIST_WORDS8; w += blockDim.x) part[w] = lh[w];
    } else {
        for (int w = threadIdx.x; w < HIST_WORDS8; w += blockDim.x){
            uint32_t v = lh[w];
            if (v){
                uint32_t c0 = v & 255u, c1 = (v >> 8) & 255u, c2 = (v >> 16) & 255u, c3 = v >> 24;
                if (c0) atomicAdd(&out32[4*w + 0], c0);
                if (c1) atomicAdd(&out32[4*w + 1], c1);
                if (c2) atomicAdd(&out32[4*w + 2], c2);
                if (c3) atomicAdd(&out32[4*w + 3], c3);
            }
        }
    }
}

// 256 blocks x 1024 threads. Block b produces exactly histogram ROW b
// (bins [b*256, (b+1)*256)) and also emits rsum[b] and csum contributions.
__global__ void __launch_bounds__(1024)
reduce_kernel(const uint32_t* __restrict__ partials, uint32_t* __restrict__ hist,
              uint32_t* __restrict__ rsum, uint32_t* __restrict__ csum, int nparts){
    __shared__ uint32_t sm[64][16][16];  // [g][k][ql], 64 KB
    int t = threadIdx.x;
    int ql = t & 15, g = t >> 4;
    int per = nparts >> 6;
    uint32_t c[16];
    #pragma unroll
    for (int k = 0; k < 16; ++k) c[k] = 0;
    const uint4* base = (const uint4*)partials;
    size_t qoff = (size_t)blockIdx.x * 16 + ql;
    #pragma unroll 8
    for (int j = 0; j < per; ++j){
        uint4 v = base[(size_t)(g * per + j) * (HIST_WORDS8 / 4) + qoff];
        c[ 0] += v.x & 255u; c[ 1] += (v.x >> 8) & 255u; c[ 2] += (v.x >> 16) & 255u; c[ 3] += v.x >> 24;
        c[ 4] += v.y & 255u; c[ 5] += (v.y >> 8) & 255u; c[ 6] += (v.y >> 16) & 255u; c[ 7] += v.y >> 24;
        c[ 8] += v.z & 255u; c[ 9] += (v.z >> 8) & 255u; c[10] += (v.z >> 16) & 255u; c[11] += v.z >> 24;
        c[12] += v.w & 255u; c[13] += (v.w >> 8) & 255u; c[14] += (v.w >> 16) & 255u; c[15] += v.w >> 24;
    }
    #pragma unroll
    for (int k = 0; k < 16; ++k) sm[g][k][ql] = c[k];
    __syncthreads();
    uint32_t s = 0;
    if (t < 256){
        int q2 = t & 15;      // quad within row
        int k  = t >> 4;      // bin within quad
        #pragma unroll 8
        for (int gg = 0; gg < 64; ++gg) s += sm[gg][k][q2];
        hist[(size_t)blockIdx.x * 256 + q2 * 16 + k] = s;
        atomicAdd(&csum[q2 * 16 + k], s);
    }
    __syncthreads();                       // all sm reads done before reuse
    uint32_t* flat = &sm[0][0][0];
    if (t < 256){
        uint32_t bs = s;
        #pragma unroll
        for (int o = 32; o > 0; o >>= 1) bs += __shfl_down(bs, o, 64);
        if ((t & 63) == 0) flat[t >> 6] = bs;
    }
    __syncthreads();
    if (t == 0) rsum[blockIdx.x] = flat[0] + flat[1] + flat[2] + flat[3];
}

__device__ double bsum1024(double v, double* red, int t){
    #pragma unroll
    for (int o = 32; o > 0; o >>= 1) v += __shfl_down(v, o, 64);
    __syncthreads();
    if ((t & 63) == 0) red[t >> 6] = v;
    __syncthreads();
    if (t == 0){
        double s = 0.0;
        for (int w = 0; w < 16; ++w) s += red[w];
        v = s;
    }
    return v;  // valid in thread 0 only
}

__global__ void __launch_bounds__(1024)
finalize_kernel(const uint32_t* __restrict__ hist,
                const uint32_t* __restrict__ rsum, const uint32_t* __restrict__ csum,
                float* __restrict__ out, int n, int marg){
    __shared__ uint32_t lrs[256], lcs[256];
    __shared__ uint32_t csum4[4][256];
    __shared__ double red[16];
    int t = threadIdx.x;

    if (!marg){
        if (t < 256){ lrs[t] = rsum[t]; lcs[t] = csum[t]; }
    } else {
        // fallback: compute marginals from hist directly
        {   // rows: 4 threads per row, 16 uint4 each
            int r = t >> 2, q = t & 3;
            const uint4* hp = (const uint4*)(hist + r * 256 + q * 64);
            uint32_t s = 0;
            #pragma unroll
            for (int k = 0; k < 16; ++k){ uint4 v = hp[k]; s += v.x + v.y + v.z + v.w; }
            s += __shfl_down(s, 2, 64);
            s += __shfl_down(s, 1, 64);
            if (q == 0) lrs[r] = s;
        }
        {   // cols: c across lanes, 4 row-groups
            int c = t & 255, g = t >> 8;
            const uint32_t* hp = hist + g * 64 * 256 + c;
            uint32_t s = 0;
            #pragma unroll 8
            for (int r = 0; r < 64; ++r) s += hp[r * 256];
            csum4[g][c] = s;
        }
        __syncthreads();
        if (t < 256) lcs[t] = csum4[0][t] + csum4[1][t] + csum4[2][t] + csum4[3][t];
    }
    __syncthreads();

    const double invn = 1.0 / (double)n;
    const double dn = (double)n;

    // MI: wave g handles rows g + 16k via uint4 (lane q covers cols 4q..4q+3).
    double mi = 0.0;
    {
        int q = t & 63, g = t >> 6;
        const uint4* h4 = (const uint4*)hist;
        for (int k = 0; k < 16; ++k){
            int r = g * 16 + k;
            uint4 v = h4[r * 64 + q];
            double rs = (double)lrs[r];
            uint32_t cc[4] = {v.x, v.y, v.z, v.w};
            #pragma unroll
            for (int j = 0; j < 4; ++j){
                if (cc[j]){
                    double ratio = ((double)cc[j] * dn) / (rs * (double)lcs[q * 4 + j]);
                    mi += (double)cc[j] * (double)logf((float)ratio);
                }
            }
        }
        mi *= invn;
    }
    double hx = 0.0, hy = 0.0;
    if (t < 256){
        double px = (double)lrs[t] * invn;
        double py = (double)lcs[t] * invn;
        hx = px * log(px + 1e-8);
        hy = py * log(py + 1e-8);
    }
    double mi_s = bsum1024(mi, red, t);
    double hx_s = bsum1024(hx, red, t);
    double hy_s = bsum1024(hy, red, t);
    if (t == 0){
        double h_x = -hx_s, h_y = -hy_s;
        double nmi = mi_s / (sqrt(h_x * h_y) + 1e-8);
        out[0] = (float)(-nmi);
    }
}

extern "C" void kernel_launch(void* const* d_in, const int* in_sizes, int n_in,
                              void* d_out, int out_size, void* d_ws, size_t ws_size,
                              hipStream_t stream){
    const f4* x = (const f4*)d_in[0];
    const f4* y = (const f4*)d_in[1];
    float* out = (float*)d_out;
    uint32_t* ws = (uint32_t*)d_ws;
    uint32_t* hist = ws;                        // 65536 words
    uint32_t* mm   = ws + HIST_BINS;            // 4 words (padded to 64)
    uint32_t* rsum = ws + HIST_BINS + 64;       // 256 words
    uint32_t* csum = ws + HIST_BINS + 64 + 256; // 256 words
    uint32_t* partials = ws + HIST_BINS + 64 + 512;

    int n  = in_sizes[0];
    int n4 = n / 4;

    size_t head = (size_t)HIST_BINS + 64 + 512;
    size_t need512 = (head + (size_t)512 * HIST_WORDS8) * 4;
    size_t need256 = (head + (size_t)256 * HIST_WORDS8) * 4;
    int nblk, atomic_flush;
    if (ws_size >= need512)      { nblk = 512; atomic_flush = 0; }
    else if (ws_size >= need256) { nblk = 256; atomic_flush = 0; }
    else                         { nblk = 512; atomic_flush = 1; }

    if (atomic_flush)
        hipMemsetAsync(hist, 0, HIST_BINS * sizeof(uint32_t), stream);
    init_kernel<<<1, 256, 0, stream>>>(mm, csum);
    minmax_kernel<<<512, 1024, 0, stream>>>(x, y, mm, n4, 256);
    hist_kernel<<<nblk, 1024, 0, stream>>>(x, y, mm,
                                           atomic_flush ? hist : partials, n4, atomic_flush);
    if (!atomic_flush)
        reduce_kernel<<<256, 1024, 0, stream>>>(partials, hist, rsum, csum, nblk);
    finalize_kernel<<<1, 1024, 0, stream>>>(hist, rsum, csum, out, n, atomic_flush);
}